// Round 5
// baseline (519.909 us; speedup 1.0000x reference)
//
#include <hip/hip_runtime.h>

#define BATCH  4096
#define NROWS  8192
#define LATENT 2048
#define ZDIM   128
#define PRIORc       0.3f
#define PRIOR_PRIMEc 0.5f
// sqrt(2 * log2(e)): folds both 1/TEMP and the ln->log2 conversion into zn,
// so exp(sim/TEMP) == exp2(dot of scaled vectors) -> bare v_exp_f32.
#define ZSCALE 1.6986436f

typedef __attribute__((ext_vector_type(8))) short bf16x8;  // 8 bf16 = 4 VGPRs
typedef __attribute__((ext_vector_type(4))) float f32x4;   // MFMA C/D + NT loads

__device__ inline unsigned short f2bf_rne(float f) {
    unsigned int u = __float_as_uint(f);
    u = u + 0x7fffu + ((u >> 16) & 1u);
    return (unsigned short)(u >> 16);
}
__device__ inline float bf2f(unsigned short h) {
    return __uint_as_float(((unsigned int)h) << 16);
}
__device__ inline float wave_reduce_sum(float v) {
#pragma unroll
    for (int m = 1; m < 64; m <<= 1) v += __shfl_xor(v, m, 64);
    return v;
}

// ---------------------------------------------------------------------------
// One wave per positive pair (r, r+BATCH):
//  - normalize both rows, scale by ZSCALE, cast bf16, store MFMA-swizzled
//  - exact fp32 positive-pair logit (natural-log domain)
//  - expdiag[row] = exp2(self-dot of the ROUNDED bf16 row) == the diagonal
//    term the sim MFMA will produce (sim kernel no longer masks it)
//  - also zero-inits S_row and the completion counter (replaces memset node)
// Swizzle: chunk (g*4+kt), lane q*16+(row&15) holds k = kt*32+q*8 .. +7
// ---------------------------------------------------------------------------
__global__ void k_zprep(const float* __restrict__ z_i, const float* __restrict__ z_j,
                        unsigned short* __restrict__ znb, float* __restrict__ pos,
                        float* __restrict__ expdiag, float* __restrict__ S_row,
                        unsigned int* __restrict__ counter) {
    int gid = blockIdx.x * 256 + threadIdx.x;
    if (gid < NROWS) S_row[gid] = 0.f;
    if (gid == 0) *counter = 0u;

    int wave = threadIdx.x >> 6, lane = threadIdx.x & 63;
    int r = blockIdx.x * 4 + wave;            // 0..4095
    int p = r + BATCH;
    float2 a = ((const float2*)(z_i + (size_t)r * ZDIM))[lane];
    float2 c = ((const float2*)(z_j + (size_t)r * ZDIM))[lane];
    float sa = wave_reduce_sum(a.x * a.x + a.y * a.y);
    float sc = wave_reduce_sum(c.x * c.x + c.y * c.y);
    float dd = wave_reduce_sum(a.x * c.x + a.y * c.y);
    float inva = 1.f / fmaxf(sqrtf(sa), 1e-8f);
    float invc = 1.f / fmaxf(sqrtf(sc), 1e-8f);
    if (lane == 0) {
        float pv = 2.0f * dd * inva * invc;   // cos-sim / TEMP, exact fp32
        pos[r] = pv;
        pos[p] = pv;
    }
    int kt = lane >> 4;
    int q  = (lane >> 2) & 3;
    int j  = (lane & 3) * 2;
    int lrow = q * 16;
    float fa = inva * ZSCALE, fc = invc * ZSCALE;
    ushort2 wa, wc;
    wa.x = f2bf_rne(a.x * fa); wa.y = f2bf_rne(a.y * fa);
    wc.x = f2bf_rne(c.x * fc); wc.y = f2bf_rne(c.y * fc);
    {   // row r (from z_i)
        size_t off = ((size_t)((r >> 4) * 4 + kt) * 64 + (lrow + (r & 15))) * 8 + j;
        *(ushort2*)(znb + off) = wa;
    }
    {   // row p (from z_j)
        size_t off = ((size_t)((p >> 4) * 4 + kt) * 64 + (lrow + (p & 15))) * 8 + j;
        *(ushort2*)(znb + off) = wc;
    }
    // self-dot of the rounded values == MFMA diagonal (log2 domain)
    float xa = bf2f(wa.x), ya = bf2f(wa.y);
    float xc = bf2f(wc.x), yc = bf2f(wc.y);
    float sda = wave_reduce_sum(xa * xa + ya * ya);
    float sdc = wave_reduce_sum(xc * xc + yc * yc);
    if (lane == 0) {
        expdiag[r] = __builtin_amdgcn_exp2f(sda);
        expdiag[p] = __builtin_amdgcn_exp2f(sdc);
    }
}

// ---------------------------------------------------------------------------
// Mega kernel: blocks [0,1024) = sim (compute-bound), [1024,3072) = logits
// (HBM-bound, nontemporal so the h-stream doesn't evict znb from L2).
// sim: per block 128-row x 512-col; A frags register-resident; B frags
// software-pipelined; no diag masking (subtracted via expdiag in the final);
// bare exp2 epilogue; per-lane row-sums; one shuffle+atomic per wave.
// Last-finishing block (fence + counter) does the final scalar reduction.
// ---------------------------------------------------------------------------
__global__ void __launch_bounds__(256, 3) k_mega(
        const unsigned short* __restrict__ znb, float* __restrict__ S_row,
        const float* __restrict__ h_i, const float* __restrict__ h_j,
        const float* __restrict__ W, const float* __restrict__ bb,
        float* __restrict__ logits, const float* __restrict__ pos,
        const float* __restrict__ expdiag, const int* __restrict__ target,
        const float* __restrict__ w_onnpu, unsigned int* __restrict__ counter,
        float* __restrict__ out) {
    int bid = blockIdx.x;
    int lane = threadIdx.x & 63, wave = threadIdx.x >> 6;
    if (bid < 1024) {
        int q = lane >> 4, t = lane & 15;
        int row0 = (bid & 63) * 128 + (wave >> 1) * 64;
        int gA = row0 >> 4;
        const bf16x8* zf = (const bf16x8*)znb;

        bf16x8 a[4][4];
#pragma unroll
        for (int mt = 0; mt < 4; ++mt)
#pragma unroll
            for (int kt = 0; kt < 4; ++kt)
                a[mt][kt] = zf[(size_t)((gA + mt) * 4 + kt) * 64 + lane];

        float s[16];
#pragma unroll
        for (int i = 0; i < 16; ++i) s[i] = 0.f;

        int colbase = (bid >> 6) * 512 + (wave & 1) * 64;
        int cb4 = colbase >> 4;
        bf16x8 b[4];
#pragma unroll
        for (int kt = 0; kt < 4; ++kt)
            b[kt] = zf[(size_t)(cb4 * 4 + kt) * 64 + lane];

        f32x4 zero = {0.f, 0.f, 0.f, 0.f};
#pragma unroll 1
        for (int it = 0; it < 4; ++it) {
#pragma unroll
            for (int nt = 0; nt < 4; ++nt) {
                bf16x8 bn[4];
                if (!(it == 3 && nt == 3)) {
                    int ng = cb4 + (nt == 3 ? (it + 1) * 8 : it * 8 + nt + 1);
#pragma unroll
                    for (int kt = 0; kt < 4; ++kt)
                        bn[kt] = zf[(size_t)(ng * 4 + kt) * 64 + lane];
                }
                f32x4 acc[4];
#pragma unroll
                for (int mt = 0; mt < 4; ++mt)   // kt=0 consumes literal-zero C
                    acc[mt] = __builtin_amdgcn_mfma_f32_16x16x32_bf16(a[mt][0], b[0], zero, 0, 0, 0);
#pragma unroll
                for (int kt = 1; kt < 4; ++kt)
#pragma unroll
                    for (int mt = 0; mt < 4; ++mt)
                        acc[mt] = __builtin_amdgcn_mfma_f32_16x16x32_bf16(a[mt][kt], b[kt], acc[mt], 0, 0, 0);
#pragma unroll
                for (int mt = 0; mt < 4; ++mt)
#pragma unroll
                    for (int reg = 0; reg < 4; ++reg)
                        s[mt * 4 + reg] += __builtin_amdgcn_exp2f(acc[mt][reg]);
#pragma unroll
                for (int kt = 0; kt < 4; ++kt) b[kt] = bn[kt];
            }
        }
#pragma unroll
        for (int i = 0; i < 16; ++i) {
            float v = s[i];
            v += __shfl_xor(v, 1, 64);
            v += __shfl_xor(v, 2, 64);
            v += __shfl_xor(v, 4, 64);
            v += __shfl_xor(v, 8, 64);
            if (t == 0) atomicAdd(&S_row[row0 + (i >> 2) * 16 + q * 4 + (i & 3)], v);
        }
    } else {
        int r = (bid - 1024) * 4 + wave;
        const float* h = (r < BATCH) ? (h_i + (size_t)r * LATENT)
                                     : (h_j + (size_t)(r - BATCH) * LATENT);
        const f32x4* h4 = (const f32x4*)h;
        const f32x4* w4 = (const f32x4*)W;
        float s = 0.f;
#pragma unroll
        for (int itr = 0; itr < 8; ++itr) {
            f32x4 av = __builtin_nontemporal_load(&h4[itr * 64 + lane]);
            f32x4 wv = w4[itr * 64 + lane];
            s += av.x * wv.x + av.y * wv.y + av.z * wv.z + av.w * wv.w;
        }
        s = wave_reduce_sum(s);
        if (lane == 0) logits[r] = s + bb[0];
    }

    // ---- last-block-done: fused final reduction ----
    __shared__ bool is_last;
    __syncthreads();          // all waves of this block finished their writes
    __threadfence();          // release this block's stores device-wide
    if (threadIdx.x == 0)
        is_last = (atomicAdd(counter, 1u) == (unsigned)(gridDim.x - 1));
    __syncthreads();
    if (!is_last) return;
    __threadfence();          // acquire all other blocks' stores

    float nt_s = 0.f;
    for (int r = threadIdx.x; r < NROWS; r += 256)
        nt_s += __logf(S_row[r] - expdiag[r]) - pos[r];
    float v[8];
#pragma unroll
    for (int i = 0; i < 8; ++i) v[i] = 0.f;
    for (int r = threadIdx.x; r < BATCH; r += 256) {
        float li = logits[r], lj = logits[BATCH + r];
        bool p = (target[r] == 1);
        float si_n = 1.f / (1.f + __expf(li));
        float si_p = 1.f / (1.f + __expf(-li));
        float sj_n = 1.f / (1.f + __expf(lj));
        float sj_p = 1.f / (1.f + __expf(-lj));
        v[0] += p ? 1.f : 0.f;
        v[1] += p ? 0.f : 1.f;
        v[2] += p ? si_n : 0.f;
        v[3] += p ? si_p : 0.f;
        v[4] += p ? 0.f : si_p;
        v[5] += p ? sj_n : 0.f;
        v[6] += p ? sj_p : 0.f;
        v[7] += p ? 0.f : sj_p;
    }
    __shared__ float red[4][9];
    nt_s = wave_reduce_sum(nt_s);
#pragma unroll
    for (int i = 0; i < 8; ++i) v[i] = wave_reduce_sum(v[i]);
    if (lane == 0) {
        red[wave][0] = nt_s;
#pragma unroll
        for (int i = 0; i < 8; ++i) red[wave][1 + i] = v[i];
    }
    __syncthreads();
    if (threadIdx.x == 0) {
        float t[9];
#pragma unroll
        for (int i = 0; i < 9; ++i)
            t[i] = red[0][i] + red[1][i] + red[2][i] + red[3][i];
        float ntxent = t[0] / (float)NROWS;
        float np = fmaxf(1.f, t[1]), nu = fmaxf(1.f, t[2]);
        float pr_i = PRIOR_PRIMEc / np * t[3];
        float nr_i = (1.f - PRIOR_PRIMEc) / (nu * (1.f - PRIORc)) * t[5]
                   - (1.f - PRIOR_PRIMEc) * PRIORc / (np * (1.f - PRIORc)) * t[4];
        float li_loss = (nr_i < 0.f) ? -nr_i : (pr_i + nr_i);
        float pr_j = PRIOR_PRIMEc / np * t[6];
        float nr_j = (1.f - PRIOR_PRIMEc) / (nu * (1.f - PRIORc)) * t[8]
                   - (1.f - PRIOR_PRIMEc) * PRIORc / (np * (1.f - PRIORc)) * t[7];
        float lj_loss = (nr_j < 0.f) ? -nr_j : (pr_j + nr_j);
        float onnpu = 0.5f * (li_loss + lj_loss);
        float w = w_onnpu[0];
        out[0] = w * onnpu + (1.f - w) * ntxent;
    }
}

extern "C" void kernel_launch(void* const* d_in, const int* in_sizes, int n_in,
                              void* d_out, int out_size, void* d_ws, size_t ws_size,
                              hipStream_t stream) {
    const float* h_i = (const float*)d_in[0];
    const float* h_j = (const float*)d_in[1];
    const float* z_i = (const float*)d_in[2];
    const float* z_j = (const float*)d_in[3];
    const int* target = (const int*)d_in[4];
    const float* W = (const float*)d_in[5];
    const float* b = (const float*)d_in[6];
    const float* w_onnpu = (const float*)d_in[7];

    char* ws = (char*)d_ws;
    unsigned short* znb = (unsigned short*)ws;                    // 2 MB swizzled bf16
    float* S_row   = (float*)(ws + 2097152);                      // 32 KB
    unsigned int* counter = (unsigned int*)(ws + 2097152 + 32768);// 4 B (+pad)
    float* pos     = (float*)(ws + 2097152 + 32768 + 256);        // 32 KB
    float* logits  = (float*)(ws + 2097152 + 65536 + 256);        // 32 KB
    float* expdiag = (float*)(ws + 2097152 + 98304 + 256);        // 32 KB
    float* out = (float*)d_out;

    k_zprep<<<1024, 256, 0, stream>>>(z_i, z_j, znb, pos, expdiag, S_row, counter);
    k_mega<<<3072, 256, 0, stream>>>(znb, S_row, h_i, h_j, W, b, logits,
                                     pos, expdiag, target, w_onnpu, counter, out);
}

// Round 6
// 144.573 us; speedup vs baseline: 3.5962x; 3.5962x over previous
//
#include <hip/hip_runtime.h>

#define BATCH  4096
#define NROWS  8192
#define LATENT 2048
#define ZDIM   128
#define PRIORc       0.3f
#define PRIOR_PRIMEc 0.5f
// sqrt(2 * log2(e)): folds both 1/TEMP and the ln->log2 conversion into zn,
// so exp(sim/TEMP) == exp2(dot of scaled vectors) -> bare v_exp_f32.
#define ZSCALE 1.6986436f

typedef __attribute__((ext_vector_type(8))) short bf16x8;  // 8 bf16 = 4 VGPRs
typedef __attribute__((ext_vector_type(4))) float f32x4;   // MFMA C/D + NT loads

__device__ inline unsigned short f2bf_rne(float f) {
    unsigned int u = __float_as_uint(f);
    u = u + 0x7fffu + ((u >> 16) & 1u);
    return (unsigned short)(u >> 16);
}
__device__ inline float bf2f(unsigned short h) {
    return __uint_as_float(((unsigned int)h) << 16);
}
__device__ inline float wave_reduce_sum(float v) {
#pragma unroll
    for (int m = 1; m < 64; m <<= 1) v += __shfl_xor(v, m, 64);
    return v;
}

// ---------------------------------------------------------------------------
// One wave per positive pair (r, r+BATCH):
//  - normalize both rows, scale by ZSCALE, cast bf16, store MFMA-swizzled
//  - exact fp32 positive-pair logit (natural-log domain)
//  - expdiag[row] = exp2(self-dot of the ROUNDED bf16 row) == the diagonal
//    term the sim MFMA will produce (sim kernel does NOT mask the diagonal)
//  - zero-inits S_row (replaces the memset node)
// Swizzle: chunk (g*4+kt), lane q*16+(row&15) holds k = kt*32+q*8 .. +7
// NOTE: no grid-wide fences anywhere — R5 showed __threadfence() (L2
// writeback+invalidate) from 3072 blocks thrashes znb out of L2 (5x refetch,
// 136->520us). Kernel boundaries provide the coherence instead.
// ---------------------------------------------------------------------------
__global__ void k_zprep(const float* __restrict__ z_i, const float* __restrict__ z_j,
                        unsigned short* __restrict__ znb, float* __restrict__ pos,
                        float* __restrict__ expdiag, float* __restrict__ S_row) {
    int gid = blockIdx.x * 256 + threadIdx.x;
    if (gid < NROWS) S_row[gid] = 0.f;

    int wave = threadIdx.x >> 6, lane = threadIdx.x & 63;
    int r = blockIdx.x * 4 + wave;            // 0..4095
    int p = r + BATCH;
    float2 a = ((const float2*)(z_i + (size_t)r * ZDIM))[lane];
    float2 c = ((const float2*)(z_j + (size_t)r * ZDIM))[lane];
    float sa = wave_reduce_sum(a.x * a.x + a.y * a.y);
    float sc = wave_reduce_sum(c.x * c.x + c.y * c.y);
    float dd = wave_reduce_sum(a.x * c.x + a.y * c.y);
    float inva = 1.f / fmaxf(sqrtf(sa), 1e-8f);
    float invc = 1.f / fmaxf(sqrtf(sc), 1e-8f);
    if (lane == 0) {
        float pv = 2.0f * dd * inva * invc;   // cos-sim / TEMP, exact fp32
        pos[r] = pv;
        pos[p] = pv;
    }
    int kt = lane >> 4;
    int q  = (lane >> 2) & 3;
    int j  = (lane & 3) * 2;
    int lrow = q * 16;
    float fa = inva * ZSCALE, fc = invc * ZSCALE;
    ushort2 wa, wc;
    wa.x = f2bf_rne(a.x * fa); wa.y = f2bf_rne(a.y * fa);
    wc.x = f2bf_rne(c.x * fc); wc.y = f2bf_rne(c.y * fc);
    {   // row r (from z_i)
        size_t off = ((size_t)((r >> 4) * 4 + kt) * 64 + (lrow + (r & 15))) * 8 + j;
        *(ushort2*)(znb + off) = wa;
    }
    {   // row p (from z_j)
        size_t off = ((size_t)((p >> 4) * 4 + kt) * 64 + (lrow + (p & 15))) * 8 + j;
        *(ushort2*)(znb + off) = wc;
    }
    // self-dot of the rounded values == MFMA diagonal (log2 domain)
    float xa = bf2f(wa.x), ya = bf2f(wa.y);
    float xc = bf2f(wc.x), yc = bf2f(wc.y);
    float sda = wave_reduce_sum(xa * xa + ya * ya);
    float sdc = wave_reduce_sum(xc * xc + yc * yc);
    if (lane == 0) {
        expdiag[r] = __builtin_amdgcn_exp2f(sda);
        expdiag[p] = __builtin_amdgcn_exp2f(sdc);
    }
}

// ---------------------------------------------------------------------------
// Mega kernel: blocks [0,1024) = sim (compute-bound), [1024,3072) = logits
// (HBM-bound, nontemporal h-loads so the 64MB stream doesn't evict znb).
// sim: per block 128-row x 512-col; A frags register-resident; B frags
// software-pipelined; full row-sum incl. diagonal (subtracted in k_final);
// bare exp2 epilogue; per-lane row-sums; one shuffle+atomic per wave.
// ---------------------------------------------------------------------------
__global__ void __launch_bounds__(256, 3) k_mega(
        const unsigned short* __restrict__ znb, float* __restrict__ S_row,
        const float* __restrict__ h_i, const float* __restrict__ h_j,
        const float* __restrict__ W, const float* __restrict__ bb,
        float* __restrict__ logits) {
    int bid = blockIdx.x;
    int lane = threadIdx.x & 63, wave = threadIdx.x >> 6;
    if (bid < 1024) {
        int q = lane >> 4, t = lane & 15;
        int row0 = (bid & 63) * 128 + (wave >> 1) * 64;
        int gA = row0 >> 4;
        const bf16x8* zf = (const bf16x8*)znb;

        bf16x8 a[4][4];
#pragma unroll
        for (int mt = 0; mt < 4; ++mt)
#pragma unroll
            for (int kt = 0; kt < 4; ++kt)
                a[mt][kt] = zf[(size_t)((gA + mt) * 4 + kt) * 64 + lane];

        float s[16];
#pragma unroll
        for (int i = 0; i < 16; ++i) s[i] = 0.f;

        int colbase = (bid >> 6) * 512 + (wave & 1) * 64;
        int cb4 = colbase >> 4;
        bf16x8 b[4];
#pragma unroll
        for (int kt = 0; kt < 4; ++kt)
            b[kt] = zf[(size_t)(cb4 * 4 + kt) * 64 + lane];

        f32x4 zero = {0.f, 0.f, 0.f, 0.f};
#pragma unroll 1
        for (int it = 0; it < 4; ++it) {
#pragma unroll
            for (int nt = 0; nt < 4; ++nt) {
                bf16x8 bn[4];
                if (!(it == 3 && nt == 3)) {
                    int ng = cb4 + (nt == 3 ? (it + 1) * 8 : it * 8 + nt + 1);
#pragma unroll
                    for (int kt = 0; kt < 4; ++kt)
                        bn[kt] = zf[(size_t)(ng * 4 + kt) * 64 + lane];
                }
                f32x4 acc[4];
#pragma unroll
                for (int mt = 0; mt < 4; ++mt)   // kt=0 consumes literal-zero C
                    acc[mt] = __builtin_amdgcn_mfma_f32_16x16x32_bf16(a[mt][0], b[0], zero, 0, 0, 0);
#pragma unroll
                for (int kt = 1; kt < 4; ++kt)
#pragma unroll
                    for (int mt = 0; mt < 4; ++mt)
                        acc[mt] = __builtin_amdgcn_mfma_f32_16x16x32_bf16(a[mt][kt], b[kt], acc[mt], 0, 0, 0);
#pragma unroll
                for (int mt = 0; mt < 4; ++mt)
#pragma unroll
                    for (int reg = 0; reg < 4; ++reg)
                        s[mt * 4 + reg] += __builtin_amdgcn_exp2f(acc[mt][reg]);
#pragma unroll
                for (int kt = 0; kt < 4; ++kt) b[kt] = bn[kt];
            }
        }
#pragma unroll
        for (int i = 0; i < 16; ++i) {
            float v = s[i];
            v += __shfl_xor(v, 1, 64);
            v += __shfl_xor(v, 2, 64);
            v += __shfl_xor(v, 4, 64);
            v += __shfl_xor(v, 8, 64);
            if (t == 0) atomicAdd(&S_row[row0 + (i >> 2) * 16 + q * 4 + (i & 3)], v);
        }
    } else {
        int r = (bid - 1024) * 4 + wave;
        const float* h = (r < BATCH) ? (h_i + (size_t)r * LATENT)
                                     : (h_j + (size_t)(r - BATCH) * LATENT);
        const f32x4* h4 = (const f32x4*)h;
        const f32x4* w4 = (const f32x4*)W;
        float s = 0.f;
#pragma unroll
        for (int itr = 0; itr < 8; ++itr) {
            f32x4 av = __builtin_nontemporal_load(&h4[itr * 64 + lane]);
            f32x4 wv = w4[itr * 64 + lane];
            s += av.x * wv.x + av.y * wv.y + av.z * wv.z + av.w * wv.w;
        }
        s = wave_reduce_sum(s);
        if (lane == 0) logits[r] = s + bb[0];
    }
}

// Single block: nnPU risk from logits+target, NT-Xent from S_row (minus the
// bf16-exact diagonal term) + pos, weighted combine.
__global__ void k_final(const float* __restrict__ S_row, const float* __restrict__ pos,
                        const float* __restrict__ expdiag,
                        const float* __restrict__ logits, const int* __restrict__ target,
                        const float* __restrict__ w_onnpu, float* __restrict__ out) {
    float nt_s = 0.f;
    for (int r = threadIdx.x; r < NROWS; r += 1024)
        nt_s += __logf(S_row[r] - expdiag[r]) - pos[r];
    float v[8];
#pragma unroll
    for (int i = 0; i < 8; ++i) v[i] = 0.f;
    for (int r = threadIdx.x; r < BATCH; r += 1024) {
        float li = logits[r], lj = logits[BATCH + r];
        bool p = (target[r] == 1);
        float si_n = 1.f / (1.f + __expf(li));
        float si_p = 1.f / (1.f + __expf(-li));
        float sj_n = 1.f / (1.f + __expf(lj));
        float sj_p = 1.f / (1.f + __expf(-lj));
        v[0] += p ? 1.f : 0.f;
        v[1] += p ? 0.f : 1.f;
        v[2] += p ? si_n : 0.f;
        v[3] += p ? si_p : 0.f;
        v[4] += p ? 0.f : si_p;
        v[5] += p ? sj_n : 0.f;
        v[6] += p ? sj_p : 0.f;
        v[7] += p ? 0.f : sj_p;
    }
    __shared__ float red[16][9];
    int wave = threadIdx.x >> 6, lane = threadIdx.x & 63;
    nt_s = wave_reduce_sum(nt_s);
#pragma unroll
    for (int i = 0; i < 8; ++i) v[i] = wave_reduce_sum(v[i]);
    if (lane == 0) {
        red[wave][0] = nt_s;
#pragma unroll
        for (int i = 0; i < 8; ++i) red[wave][1 + i] = v[i];
    }
    __syncthreads();
    if (threadIdx.x == 0) {
        float t[9];
#pragma unroll
        for (int i = 0; i < 9; ++i) {
            float acc = 0.f;
#pragma unroll
            for (int wv = 0; wv < 16; ++wv) acc += red[wv][i];
            t[i] = acc;
        }
        float ntxent = t[0] / (float)NROWS;
        float np = fmaxf(1.f, t[1]), nu = fmaxf(1.f, t[2]);
        float pr_i = PRIOR_PRIMEc / np * t[3];
        float nr_i = (1.f - PRIOR_PRIMEc) / (nu * (1.f - PRIORc)) * t[5]
                   - (1.f - PRIOR_PRIMEc) * PRIORc / (np * (1.f - PRIORc)) * t[4];
        float li_loss = (nr_i < 0.f) ? -nr_i : (pr_i + nr_i);
        float pr_j = PRIOR_PRIMEc / np * t[6];
        float nr_j = (1.f - PRIOR_PRIMEc) / (nu * (1.f - PRIORc)) * t[8]
                   - (1.f - PRIOR_PRIMEc) * PRIORc / (np * (1.f - PRIORc)) * t[7];
        float lj_loss = (nr_j < 0.f) ? -nr_j : (pr_j + nr_j);
        float onnpu = 0.5f * (li_loss + lj_loss);
        float w = w_onnpu[0];
        out[0] = w * onnpu + (1.f - w) * ntxent;
    }
}

extern "C" void kernel_launch(void* const* d_in, const int* in_sizes, int n_in,
                              void* d_out, int out_size, void* d_ws, size_t ws_size,
                              hipStream_t stream) {
    const float* h_i = (const float*)d_in[0];
    const float* h_j = (const float*)d_in[1];
    const float* z_i = (const float*)d_in[2];
    const float* z_j = (const float*)d_in[3];
    const int* target = (const int*)d_in[4];
    const float* W = (const float*)d_in[5];
    const float* b = (const float*)d_in[6];
    const float* w_onnpu = (const float*)d_in[7];

    char* ws = (char*)d_ws;
    unsigned short* znb = (unsigned short*)ws;                    // 2 MB swizzled bf16
    float* S_row   = (float*)(ws + 2097152);                      // 32 KB
    float* pos     = (float*)(ws + 2097152 + 32768);              // 32 KB
    float* logits  = (float*)(ws + 2097152 + 65536);              // 32 KB
    float* expdiag = (float*)(ws + 2097152 + 98304);              // 32 KB
    float* out = (float*)d_out;

    k_zprep<<<1024, 256, 0, stream>>>(z_i, z_j, znb, pos, expdiag, S_row);
    k_mega<<<3072, 256, 0, stream>>>(znb, S_row, h_i, h_j, W, b, logits);
    k_final<<<1, 1024, 0, stream>>>(S_row, pos, expdiag, logits, target, w_onnpu, out);
}